// Round 13
// baseline (85.709 us; speedup 1.0000x reference)
//
#include <hip/hip_runtime.h>
#include <math.h>

#define BQ 8192
#define HD 1024
#define NE 8
#define CAP 1280

#define BM 256
#define BN 128
#define BK 64            // fp8 elements per K-step (64B rows, k-interleaved format)
#define NRT 5            // row tiles per expert (CAP/BM)
#define TILES_PER_E 40   // 8 col * 5 rt

// k-interleaved segment format (64B = one BK slice of one row):
//   chunk c (16B) = bytes {k: 8c..8c+7} ++ {k: 32+8c..32+8c+7},  c = 0..3
// One ds_read_b128 at chunk h gives both K-half operands for MFMA lane (r,h).

// ---------------- workspace layout (bytes) ----------------
#define WS_CURSOR   0           // int[NE] (final == per-expert count)
#define WS_TICK     32          // int[NE] gemm work queue
#define WS_S        64          // float[NE]
#define WS_ZSUM     96          // float
#define WS_CESUM    100         // float
#define WS_ROWLIST  128         // int[NE*CAP] = 40960 -> ends 41088
#define WS_LOGITS2  41088       // float[NE*CAP*2] = 81920 -> ends 123008
#define WS_HEAD     123008      // memset size
#define WS_XC       123008      // fp8 xc [NE][CAP][HD] = 10485760 -> ends 10608768
#define WS_W1T      10608768    // fp8 w1^T*8 [NE][n][k] = 8388608

using f32x4  = __attribute__((ext_vector_type(4))) float;

__device__ __forceinline__ float gelu_exact(float v) {
    return 0.5f * v * (1.0f + erff(v * 0.70710678118654752440f));
}

// pack 4 floats -> 4 OCP e4m3 bytes (RNE, HW cvt)
__device__ __forceinline__ unsigned int f4_to_fp8x4(float f0, float f1, float f2, float f3) {
    int lo = __builtin_amdgcn_cvt_pk_fp8_f32(f0, f1, 0, false);
    return (unsigned int)__builtin_amdgcn_cvt_pk_fp8_f32(f2, f3, lo, true);
}

__device__ __forceinline__ void gll16(const void* g, void* l) {
    __builtin_amdgcn_global_load_lds((const __attribute__((address_space(1))) void*)g,
                                     (__attribute__((address_space(3))) void*)l, 16, 0, 0);
}

// ---- prep: router+compact (blocks 0..255) || w1 transpose (256..2303) -------
__global__ __launch_bounds__(256) void prep_kernel(
    const float* __restrict__ x, const float* __restrict__ gate_w,
    const float* __restrict__ w1,
    int* __restrict__ cursor, float* __restrict__ S, float* __restrict__ zsum,
    int* __restrict__ rowlist, unsigned char* __restrict__ xcq,
    unsigned char* __restrict__ w1tq)
{
    __shared__ __align__(16) char smem[33280];
    int tid = threadIdx.x;

    if (blockIdx.x >= 256) {
        // ---- transpose role: w1 fp32 [e][k][n] -> fp8(x8) [e][n][k-interleaved]
        char (*lt)[80] = (char (*)[80])smem;    // [n][k] bytes, 64x64 tile
        int tile = blockIdx.x - 256;          // 0..2047
        int e = tile >> 8;
        int rem = tile & 255;
        int k0 = (rem >> 4) << 6, n0 = (rem & 15) << 6;
        const float* src = w1 + ((size_t)e << 20) + (size_t)k0 * HD + n0;
        #pragma unroll
        for (int s = 0; s < 4; s++) {
            int q = tid + s * 256;
            int kk = q >> 4, n4 = q & 15;
            float4 v = *(const float4*)(src + (size_t)kk * HD + n4 * 4);
            unsigned int b = f4_to_fp8x4(v.x * 8.f, v.y * 8.f, v.z * 8.f, v.w * 8.f);
            lt[n4 * 4 + 0][kk] = (char)(b);
            lt[n4 * 4 + 1][kk] = (char)(b >> 8);
            lt[n4 * 4 + 2][kk] = (char)(b >> 16);
            lt[n4 * 4 + 3][kk] = (char)(b >> 24);
        }
        __syncthreads();
        // write 16B (groups 2q, 2q+1) as two 8B at k-interleaved positions
        int nn = tid >> 2, q = tid & 3;
        int pos0 = ((q & 1) << 5) | ((q >> 1) << 3);    // q:0->0, 1->32, 2->8, 3->40
        unsigned char* dst = w1tq + ((size_t)e << 20) + (size_t)(n0 + nn) * HD + k0;
        const unsigned long long* sp = (const unsigned long long*)&lt[nn][q * 16];
        *(unsigned long long*)(dst + pos0)      = sp[0];
        *(unsigned long long*)(dst + pos0 + 16) = sp[1];
        return;
    }

    // ---- router role: rows [bid*32, bid*32+32)
    float* gw    = (float*)smem;                    // 32 KB
    float* sS    = (float*)(smem + 32768);          // 8
    float* sZ    = (float*)(smem + 32800);          // 1
    int*   sBI   = (int*)(smem + 32832);            // 32
    int*   sSlot = (int*)(smem + 32960);            // 32
    int*   sBase = (int*)(smem + 33088);            // 8

    for (int i = tid * 4; i < NE * HD; i += 256 * 4) {
        *(float4*)(gw + i) = *(const float4*)(gate_w + i);
    }
    if (tid < NE) sS[tid] = 0.f;
    if (tid == 0) sZ[0] = 0.f;
    __syncthreads();

    int wave = tid >> 6, lane = tid & 63;
    int r0 = blockIdx.x * 32;
    float accS[NE];
    #pragma unroll
    for (int e = 0; e < NE; e++) accS[e] = 0.f;
    float accZ = 0.f;

    // phase 1: logits + per-row argmax
    #pragma unroll 1
    for (int i = 0; i < 8; i++) {
        int li = wave * 8 + i;
        int r = r0 + li;
        const float* xr = x + (size_t)r * HD;
        float acc[NE];
        #pragma unroll
        for (int e = 0; e < NE; e++) acc[e] = 0.f;
        #pragma unroll
        for (int it = 0; it < 4; it++) {
            int k = lane * 4 + it * 256;
            float4 xv = *(const float4*)(xr + k);
            #pragma unroll
            for (int e = 0; e < NE; e++) {
                const float* g = gw + e * HD + k;
                acc[e] += xv.x * g[0] + xv.y * g[1] + xv.z * g[2] + xv.w * g[3];
            }
        }
        #pragma unroll
        for (int e = 0; e < NE; e++) {
            #pragma unroll
            for (int off = 32; off > 0; off >>= 1)
                acc[e] += __shfl_xor(acc[e], off);
        }
        if (lane == 0) {
            float m = acc[0]; int bi = 0;
            #pragma unroll
            for (int e = 1; e < NE; e++) if (acc[e] > m) { m = acc[e]; bi = e; }
            float se = 0.f, ex[NE];
            #pragma unroll
            for (int e = 0; e < NE; e++) { ex[e] = expf(acc[e] - m); se += ex[e]; }
            float inv = 1.f / se;
            #pragma unroll
            for (int e = 0; e < NE; e++) accS[e] += ex[e] * inv;
            float lse = m + logf(se);
            accZ += lse * lse;
            sBI[li] = bi;
        }
    }
    if (lane == 0) {
        #pragma unroll
        for (int e = 0; e < NE; e++) atomicAdd(&sS[e], accS[e]);
        atomicAdd(sZ, accZ);
    }
    __syncthreads();

    // phase 2: block-level capacity reservation (8 atomics per block)
    if (tid < NE) {
        int cnt = 0;
        #pragma unroll
        for (int j = 0; j < 32; j++) cnt += (sBI[j] == tid);
        sBase[tid] = atomicAdd(&cursor[tid], cnt);
        atomicAdd(&S[tid], sS[tid]);
    }
    if (tid == 0) atomicAdd(zsum, sZ[0]);
    __syncthreads();

    // phase 3: per-row slot = base + rank
    if (tid < 32) {
        int bi = sBI[tid];
        int rank = 0;
        for (int j = 0; j < tid; j++) rank += (sBI[j] == bi);
        int slot = sBase[bi] + rank;
        sSlot[tid] = slot;
        if (slot < CAP) rowlist[bi * CAP + slot] = r0 + tid;
    }
    __syncthreads();

    // phase 4: re-read (hot) x rows, convert fp8, write k-interleaved slab
    #pragma unroll 1
    for (int i = 0; i < 8; i++) {
        int li = wave * 8 + i;
        int bi = sBI[li];
        int pos = sSlot[li];
        if (pos >= CAP) continue;
        const float* src = x + (size_t)(r0 + li) * HD + lane * 16;
        float4 v0 = *(const float4*)(src + 0);
        float4 v1 = *(const float4*)(src + 4);
        float4 v2 = *(const float4*)(src + 8);
        float4 v3 = *(const float4*)(src + 12);
        unsigned int g0a = f4_to_fp8x4(v0.x, v0.y, v0.z, v0.w);
        unsigned int g0b = f4_to_fp8x4(v1.x, v1.y, v1.z, v1.w);
        unsigned int g1a = f4_to_fp8x4(v2.x, v2.y, v2.z, v2.w);
        unsigned int g1b = f4_to_fp8x4(v3.x, v3.y, v3.z, v3.w);
        // lane covers segment s = lane>>2, groups 2q,2q+1 (q = lane&3)
        int s = lane >> 2, q = lane & 3;
        int pos0 = (s << 6) | ((q & 1) << 5) | ((q >> 1) << 3);
        unsigned char* dst = xcq + ((size_t)(bi * CAP + pos)) * HD;
        *(unsigned long long*)(dst + pos0)      = (unsigned long long)g0a | ((unsigned long long)g0b << 32);
        *(unsigned long long*)(dst + pos0 + 16) = (unsigned long long)g1a | ((unsigned long long)g1b << 32);
    }
}

// ---- MFMA expert GEMM (fp8): b128 fragment-pair reads, 3-buf vmcnt(3) -------
// grid 512 (2/CU), e = bid&7 (XCD-pinned). 512 thr = 8 waves (4x2), wave 64x64.
__global__ __launch_bounds__(512, 4) void expert_gemm_kernel(
    const unsigned char* __restrict__ xcq, const unsigned char* __restrict__ w1tq,
    const float* __restrict__ b1, const float* __restrict__ w2,
    const int* __restrict__ cursor, int* __restrict__ tick,
    float* __restrict__ logits2c)
{
    int e = blockIdx.x & 7;
    int cnt = cursor[e]; if (cnt > CAP) cnt = CAP;

    // 3 buffers x [A 16KB | B 8KB] = 72KB
    __shared__ __align__(16) char lds[3][24576];
    __shared__ int sTix;

    int t = threadIdx.x;
    int l = t & 63;
    // staging pre-swizzle (rule 21): chunk' = (t&3) ^ ((row>>1)&3), row = t>>2
    int scolb = ((t & 3) ^ ((t >> 3) & 3)) << 4;
    int m = t >> 2;                               // 0..127

    int wid = t >> 6;                 // 0..7
    int wr = wid >> 1, wc = wid & 1;  // 4 x 2 wave grid, wave tile 64x64
    int r = l & 15, h = l >> 4;       // frag row/col = r, k-quad = h
    // single b128 read per fragment pair (R8's proven pattern)
    int off = (h << 4) ^ (((r >> 1) & 3) << 4);

    const unsigned char* xcp  = xcq + ((size_t)e * CAP) * HD;
    const unsigned char* w1tp = w1tq + ((size_t)e << 20);

    for (;;) {
        if (t == 0) sTix = atomicAdd(&tick[e], 1);
        __syncthreads();                    // also: lds free from previous tile
        int tix = sTix;
        if (tix >= TILES_PER_E) break;
        int col = tix / NRT;                // consecutive pops share B panel
        int rt = tix - col * NRT;
        if (rt * BM >= cnt) continue;
        int n0 = col * BN;

        const unsigned char* srcA  = xcp + (size_t)(rt * BM + m) * HD + scolb;
        const unsigned char* srcA1 = srcA + (size_t)128 * HD;
        const unsigned char* srcB  = w1tp + (size_t)(n0 + m) * HD + scolb;

        f32x4 acc[4][4];
        #pragma unroll
        for (int i = 0; i < 4; i++)
            #pragma unroll
            for (int j = 0; j < 4; j++) acc[i][j] = (f32x4)(0.f);

        auto stage = [&](int bi) {
            gll16(srcA,  lds[bi] + t * 16);         srcA  += BK;
            gll16(srcA1, lds[bi] + 8192 + t * 16);  srcA1 += BK;
            gll16(srcB,  lds[bi] + 16384 + t * 16); srcB  += BK;
        };
        auto compute = [&](int bi) {
            const char* Ar = lds[bi] + (wr * 64 + r) * 64 + off;
            const char* Br = lds[bi] + 16384 + (wc * 64 + r) * 64 + off;
            longlong2 av[4], bv[4];
            #pragma unroll
            for (int i = 0; i < 4; i++) {
                av[i] = *(const longlong2*)(Ar + i * 1024);
                bv[i] = *(const longlong2*)(Br + i * 1024);
            }
            #pragma unroll
            for (int i = 0; i < 4; i++)
                #pragma unroll
                for (int j = 0; j < 4; j++)
                    acc[i][j] = __builtin_amdgcn_mfma_f32_16x16x32_fp8_fp8(av[i].x, bv[j].x, acc[i][j], 0, 0, 0);
            #pragma unroll
            for (int i = 0; i < 4; i++)
                #pragma unroll
                for (int j = 0; j < 4; j++)
                    acc[i][j] = __builtin_amdgcn_mfma_f32_16x16x32_fp8_fp8(av[i].y, bv[j].y, acc[i][j], 0, 0, 0);
        };

        stage(0); stage(1);
        int cs = 2, cc = 0;
        #pragma unroll 1
        for (int it = 0; it < HD / BK - 2; ++it) {
            asm volatile("s_waitcnt vmcnt(3)" ::: "memory");
            __builtin_amdgcn_s_barrier();
            stage(cs); cs = (cs == 2) ? 0 : cs + 1;
            compute(cc); cc = (cc == 2) ? 0 : cc + 1;
        }
        asm volatile("s_waitcnt vmcnt(3)" ::: "memory");
        __builtin_amdgcn_s_barrier();
        compute(cc); cc = (cc == 2) ? 0 : cc + 1;
        asm volatile("s_waitcnt vmcnt(0)" ::: "memory");
        __builtin_amdgcn_s_barrier();
        compute(cc);

        // epilogue: descale (w1 was x8) + bias + gelu + w2 dot + 16-lane reduce
        float b1v[4], w20v[4], w21v[4];
        #pragma unroll
        for (int j = 0; j < 4; j++) {
            int cj = n0 + wc * 64 + j * 16 + r;
            b1v[j]  = b1[e * HD + cj];
            w20v[j] = w2[((size_t)e * HD + cj) * 2 + 0];
            w21v[j] = w2[((size_t)e * HD + cj) * 2 + 1];
        }
        #pragma unroll
        for (int i = 0; i < 4; i++) {
            #pragma unroll
            for (int reg = 0; reg < 4; reg++) {
                float s0 = 0.f, s1 = 0.f;
                #pragma unroll
                for (int j = 0; j < 4; j++) {
                    float hv = gelu_exact(acc[i][j][reg] * 0.125f + b1v[j]);
                    s0 += hv * w20v[j];
                    s1 += hv * w21v[j];
                }
                #pragma unroll
                for (int offx = 1; offx < 16; offx <<= 1) {
                    s0 += __shfl_xor(s0, offx);
                    s1 += __shfl_xor(s1, offx);
                }
                if (r == 0) {
                    int lm = wr * 64 + i * 16 + 4 * h + reg;
                    int p = rt * BM + lm;
                    if (p < cnt) {
                        atomicAdd(&logits2c[(e * CAP + p) * 2 + 0], s0);
                        atomicAdd(&logits2c[(e * CAP + p) * 2 + 1], s1);
                    }
                }
            }
        }
    }
}

// ---- CE over (softmaxed) expert outputs (capacity-slot order) ---------------
__global__ __launch_bounds__(256) void ce_kernel(
    const float* __restrict__ logits2c, const float* __restrict__ b2,
    const int* __restrict__ cursor, const int* __restrict__ rowlist,
    const int* __restrict__ label, float* __restrict__ cesum)
{
    __shared__ float red[4];
    int tid = threadIdx.x;
    int s = blockIdx.x * 256 + tid;     // 0..NE*CAP-1
    int e = s / CAP;
    int local = s - e * CAP;
    int cnt = cursor[e]; if (cnt > CAP) cnt = CAP;
    float ce = 0.f;
    if (local < cnt) {
        int rr = rowlist[s];
        float l0 = logits2c[s * 2 + 0] + b2[e * 2 + 0];
        float l1 = logits2c[s * 2 + 1] + b2[e * 2 + 1];
        float mx = fmaxf(l0, l1);
        float e0 = expf(l0 - mx), e1 = expf(l1 - mx);
        float inv = 1.f / (e0 + e1);
        float p0 = e0 * inv, p1 = e1 * inv;
        float m2 = fmaxf(p0, p1);
        float z = m2 + logf(expf(p0 - m2) + expf(p1 - m2));
        float lp = ((label[rr] == 0) ? p0 : p1) - z;
        ce = -lp;
    }
    int lane = tid & 63, wave = tid >> 6;
    #pragma unroll
    for (int off = 32; off > 0; off >>= 1) ce += __shfl_xor(ce, off);
    if (lane == 0) red[wave] = ce;
    __syncthreads();
    if (tid == 0) atomicAdd(cesum, red[0] + red[1] + red[2] + red[3]);
}

// ---------------- finalize ----------------
__global__ void finalize_kernel(const float* __restrict__ S, const int* __restrict__ cursor,
                                const float* __restrict__ zsum, const float* __restrict__ cesum,
                                float* __restrict__ out)
{
    if (threadIdx.x == 0 && blockIdx.x == 0) {
        float bal = 0.f;
        for (int e = 0; e < NE; e++) bal += S[e] * (float)cursor[e];
        bal *= (float)NE / ((float)BQ * (float)BQ);
        out[0] = cesum[0] / (float)BQ + 0.01f * bal + 0.001f * (zsum[0] / (float)BQ);
    }
}

extern "C" void kernel_launch(void* const* d_in, const int* in_sizes, int n_in,
                              void* d_out, int out_size, void* d_ws, size_t ws_size,
                              hipStream_t stream) {
    const float* x      = (const float*)d_in[0];
    const int*   label  = (const int*)d_in[1];
    const float* gate_w = (const float*)d_in[2];
    const float* w1     = (const float*)d_in[3];
    const float* b1     = (const float*)d_in[4];
    const float* w2     = (const float*)d_in[5];
    const float* b2     = (const float*)d_in[6];
    float* out = (float*)d_out;

    char* ws = (char*)d_ws;
    int*   cursor   = (int*)(ws + WS_CURSOR);
    int*   tick     = (int*)(ws + WS_TICK);
    float* S        = (float*)(ws + WS_S);
    float* zsum     = (float*)(ws + WS_ZSUM);
    float* cesum    = (float*)(ws + WS_CESUM);
    int*   rowlist  = (int*)(ws + WS_ROWLIST);
    float* logits2c = (float*)(ws + WS_LOGITS2);
    unsigned char* xcq  = (unsigned char*)(ws + WS_XC);
    unsigned char* w1tq = (unsigned char*)(ws + WS_W1T);

    hipMemsetAsync(d_ws, 0, WS_HEAD, stream);

    prep_kernel<<<2304, 256, 0, stream>>>(x, gate_w, w1, cursor, S, zsum,
                                          rowlist, xcq, w1tq);
    expert_gemm_kernel<<<512, 512, 0, stream>>>(xcq, w1tq, b1, w2, cursor, tick,
                                                logits2c);
    ce_kernel<<<NE * CAP / 256, 256, 0, stream>>>(logits2c, b2, cursor, rowlist,
                                                  label, cesum);
    finalize_kernel<<<1, 64, 0, stream>>>(S, cursor, zsum, cesum, out);
}

// Round 14
// 73.290 us; speedup vs baseline: 1.1695x; 1.1695x over previous
//
#include <hip/hip_runtime.h>
#include <math.h>

#define BQ 8192
#define HD 1024
#define NE 8
#define CAP 1280

#define BM 128
#define BN 128
#define BK 64            // fp8 elements per K-step (64B rows, k-interleaved format)
#define NRT 10           // row tiles per expert (CAP/BM)
#define NCT 8            // col tiles (HD/BN)
#define TILES_PER_E 80

// k-interleaved segment format (64B = one BK slice of one row):
//   chunk c (16B) = bytes {k: 8c..8c+7} ++ {k: 32+8c..32+8c+7},  c = 0..3
// One ds_read_b128 at chunk h gives both K-half operands for MFMA lane (r,h).

// ---------------- workspace layout (bytes) ----------------
#define WS_CURSOR   0           // int[NE] (final == per-expert count)
#define WS_S        64          // float[NE]
#define WS_ZSUM     96          // float
#define WS_CESUM    100         // float
#define WS_ROWLIST  128         // int[NE*CAP] = 40960 -> ends 41088
#define WS_LOGITS2  41088       // float[NE*CAP*2] = 81920 -> ends 123008
#define WS_HEAD     123008      // memset size
#define WS_XC       123008      // fp8 xc [NE][CAP][HD] = 10485760 -> ends 10608768
#define WS_W1T      10608768    // fp8 w1^T*8 [NE][n][k] = 8388608

using f32x4  = __attribute__((ext_vector_type(4))) float;

__device__ __forceinline__ float gelu_exact(float v) {
    return 0.5f * v * (1.0f + erff(v * 0.70710678118654752440f));
}

// pack 4 floats -> 4 OCP e4m3 bytes (RNE, HW cvt)
__device__ __forceinline__ unsigned int f4_to_fp8x4(float f0, float f1, float f2, float f3) {
    int lo = __builtin_amdgcn_cvt_pk_fp8_f32(f0, f1, 0, false);
    return (unsigned int)__builtin_amdgcn_cvt_pk_fp8_f32(f2, f3, lo, true);
}

__device__ __forceinline__ void gll16(const void* g, void* l) {
    __builtin_amdgcn_global_load_lds((const __attribute__((address_space(1))) void*)g,
                                     (__attribute__((address_space(3))) void*)l, 16, 0, 0);
}

// ---- prep: router+compact (blocks 0..255) || w1 transpose (256..2303) -------
__global__ __launch_bounds__(256) void prep_kernel(
    const float* __restrict__ x, const float* __restrict__ gate_w,
    const float* __restrict__ w1,
    int* __restrict__ cursor, float* __restrict__ S, float* __restrict__ zsum,
    int* __restrict__ rowlist, unsigned char* __restrict__ xcq,
    unsigned char* __restrict__ w1tq)
{
    __shared__ __align__(16) char smem[33280];
    int tid = threadIdx.x;

    if (blockIdx.x >= 256) {
        // ---- transpose role: w1 fp32 [e][k][n] -> fp8(x8) [e][n][k-interleaved]
        char (*lt)[80] = (char (*)[80])smem;    // [n][k] bytes, 64x64 tile
        int tile = blockIdx.x - 256;          // 0..2047
        int e = tile >> 8;
        int rem = tile & 255;
        int k0 = (rem >> 4) << 6, n0 = (rem & 15) << 6;
        const float* src = w1 + ((size_t)e << 20) + (size_t)k0 * HD + n0;
        #pragma unroll
        for (int s = 0; s < 4; s++) {
            int q = tid + s * 256;
            int kk = q >> 4, n4 = q & 15;
            float4 v = *(const float4*)(src + (size_t)kk * HD + n4 * 4);
            unsigned int b = f4_to_fp8x4(v.x * 8.f, v.y * 8.f, v.z * 8.f, v.w * 8.f);
            lt[n4 * 4 + 0][kk] = (char)(b);
            lt[n4 * 4 + 1][kk] = (char)(b >> 8);
            lt[n4 * 4 + 2][kk] = (char)(b >> 16);
            lt[n4 * 4 + 3][kk] = (char)(b >> 24);
        }
        __syncthreads();
        // write 16B (groups 2q, 2q+1) as two 8B at k-interleaved positions
        int nn = tid >> 2, q = tid & 3;
        int pos0 = ((q & 1) << 5) | ((q >> 1) << 3);    // q:0->0, 1->32, 2->8, 3->40
        unsigned char* dst = w1tq + ((size_t)e << 20) + (size_t)(n0 + nn) * HD + k0;
        const unsigned long long* sp = (const unsigned long long*)&lt[nn][q * 16];
        *(unsigned long long*)(dst + pos0)      = sp[0];
        *(unsigned long long*)(dst + pos0 + 16) = sp[1];
        return;
    }

    // ---- router role: rows [bid*32, bid*32+32)
    float* gw    = (float*)smem;                    // 32 KB
    float* sS    = (float*)(smem + 32768);          // 8
    float* sZ    = (float*)(smem + 32800);          // 1
    int*   sBI   = (int*)(smem + 32832);            // 32
    int*   sSlot = (int*)(smem + 32960);            // 32
    int*   sBase = (int*)(smem + 33088);            // 8

    for (int i = tid * 4; i < NE * HD; i += 256 * 4) {
        *(float4*)(gw + i) = *(const float4*)(gate_w + i);
    }
    if (tid < NE) sS[tid] = 0.f;
    if (tid == 0) sZ[0] = 0.f;
    __syncthreads();

    int wave = tid >> 6, lane = tid & 63;
    int r0 = blockIdx.x * 32;
    float accS[NE];
    #pragma unroll
    for (int e = 0; e < NE; e++) accS[e] = 0.f;
    float accZ = 0.f;

    // phase 1: logits + per-row argmax
    #pragma unroll 1
    for (int i = 0; i < 8; i++) {
        int li = wave * 8 + i;
        int r = r0 + li;
        const float* xr = x + (size_t)r * HD;
        float acc[NE];
        #pragma unroll
        for (int e = 0; e < NE; e++) acc[e] = 0.f;
        #pragma unroll
        for (int it = 0; it < 4; it++) {
            int k = lane * 4 + it * 256;
            float4 xv = *(const float4*)(xr + k);
            #pragma unroll
            for (int e = 0; e < NE; e++) {
                const float* g = gw + e * HD + k;
                acc[e] += xv.x * g[0] + xv.y * g[1] + xv.z * g[2] + xv.w * g[3];
            }
        }
        #pragma unroll
        for (int e = 0; e < NE; e++) {
            #pragma unroll
            for (int off = 32; off > 0; off >>= 1)
                acc[e] += __shfl_xor(acc[e], off);
        }
        if (lane == 0) {
            float m = acc[0]; int bi = 0;
            #pragma unroll
            for (int e = 1; e < NE; e++) if (acc[e] > m) { m = acc[e]; bi = e; }
            float se = 0.f, ex[NE];
            #pragma unroll
            for (int e = 0; e < NE; e++) { ex[e] = expf(acc[e] - m); se += ex[e]; }
            float inv = 1.f / se;
            #pragma unroll
            for (int e = 0; e < NE; e++) accS[e] += ex[e] * inv;
            float lse = m + logf(se);
            accZ += lse * lse;
            sBI[li] = bi;
        }
    }
    if (lane == 0) {
        #pragma unroll
        for (int e = 0; e < NE; e++) atomicAdd(&sS[e], accS[e]);
        atomicAdd(sZ, accZ);
    }
    __syncthreads();

    // phase 2: block-level capacity reservation (8 atomics per block)
    if (tid < NE) {
        int cnt = 0;
        #pragma unroll
        for (int j = 0; j < 32; j++) cnt += (sBI[j] == tid);
        sBase[tid] = atomicAdd(&cursor[tid], cnt);
        atomicAdd(&S[tid], sS[tid]);
    }
    if (tid == 0) atomicAdd(zsum, sZ[0]);
    __syncthreads();

    // phase 3: per-row slot = base + rank
    if (tid < 32) {
        int bi = sBI[tid];
        int rank = 0;
        for (int j = 0; j < tid; j++) rank += (sBI[j] == bi);
        int slot = sBase[bi] + rank;
        sSlot[tid] = slot;
        if (slot < CAP) rowlist[bi * CAP + slot] = r0 + tid;
    }
    __syncthreads();

    // phase 4: re-read (hot) x rows, convert fp8, write k-interleaved slab
    #pragma unroll 1
    for (int i = 0; i < 8; i++) {
        int li = wave * 8 + i;
        int bi = sBI[li];
        int pos = sSlot[li];
        if (pos >= CAP) continue;
        const float* src = x + (size_t)(r0 + li) * HD + lane * 16;
        float4 v0 = *(const float4*)(src + 0);
        float4 v1 = *(const float4*)(src + 4);
        float4 v2 = *(const float4*)(src + 8);
        float4 v3 = *(const float4*)(src + 12);
        unsigned int g0a = f4_to_fp8x4(v0.x, v0.y, v0.z, v0.w);
        unsigned int g0b = f4_to_fp8x4(v1.x, v1.y, v1.z, v1.w);
        unsigned int g1a = f4_to_fp8x4(v2.x, v2.y, v2.z, v2.w);
        unsigned int g1b = f4_to_fp8x4(v3.x, v3.y, v3.z, v3.w);
        // lane covers segment s = lane>>2, groups 2q,2q+1 (q = lane&3)
        int s = lane >> 2, q = lane & 3;
        int pos0 = (s << 6) | ((q & 1) << 5) | ((q >> 1) << 3);
        unsigned char* dst = xcq + ((size_t)(bi * CAP + pos)) * HD;
        *(unsigned long long*)(dst + pos0)      = (unsigned long long)g0a | ((unsigned long long)g0b << 32);
        *(unsigned long long*)(dst + pos0 + 16) = (unsigned long long)g1a | ((unsigned long long)g1b << 32);
    }
}

// ---- MFMA expert GEMM (fp8): 128x128 tiles, 4 waves, 3 blocks/CU ------------
// grid 640: e = bid&7 (XCD round-robin); tix = bid>>3: col = tix/NRT, rt = tix%NRT
// (col-major tix -> same-XCD consecutive blocks share the B panel).
__global__ __launch_bounds__(256, 3) void expert_gemm_kernel(
    const unsigned char* __restrict__ xcq, const unsigned char* __restrict__ w1tq,
    const float* __restrict__ b1, const float* __restrict__ w2,
    const int* __restrict__ cursor, float* __restrict__ logits2c)
{
    int bid = blockIdx.x;
    int e = bid & 7;
    int tix = bid >> 3;
    int col = tix / NRT;
    int rt = tix - col * NRT;
    int cnt = cursor[e]; if (cnt > CAP) cnt = CAP;
    if (rt * BM >= cnt) return;
    int n0 = col * BN;

    // 3 buffers x [A 8KB | B 8KB] = 48KB
    __shared__ __align__(16) char lds[3][16384];

    int t = threadIdx.x;
    int l = t & 63;
    // staging pre-swizzle (rule 21): chunk' = (t&3) ^ ((row>>1)&3), row = t>>2
    int scolb = ((t & 3) ^ ((t >> 3) & 3)) << 4;
    int m = t >> 2;                               // 0..63

    int wid = t >> 6;                 // 0..3
    int wr = wid >> 1, wc = wid & 1;  // 2 x 2 wave grid, wave tile 64x64
    int r = l & 15, h = l >> 4;       // frag row/col = r, k-quad = h
    // single b128 read per fragment pair (proven 0-conflict pattern)
    int off = (h << 4) ^ (((r >> 1) & 3) << 4);

    const unsigned char* xcp  = xcq + ((size_t)e * CAP) * HD;
    const unsigned char* w1tp = w1tq + ((size_t)e << 20);

    const unsigned char* srcA0 = xcp + (size_t)(rt * BM + m) * HD + scolb;
    const unsigned char* srcA1 = srcA0 + (size_t)64 * HD;
    const unsigned char* srcB0 = w1tp + (size_t)(n0 + m) * HD + scolb;
    const unsigned char* srcB1 = srcB0 + (size_t)64 * HD;

    f32x4 acc[4][4];
    #pragma unroll
    for (int i = 0; i < 4; i++)
        #pragma unroll
        for (int j = 0; j < 4; j++) acc[i][j] = (f32x4)(0.f);

    auto stage = [&](int bi) {
        gll16(srcA0, lds[bi] + t * 16);         srcA0 += BK;
        gll16(srcA1, lds[bi] + 4096 + t * 16);  srcA1 += BK;
        gll16(srcB0, lds[bi] + 8192 + t * 16);  srcB0 += BK;
        gll16(srcB1, lds[bi] + 12288 + t * 16); srcB1 += BK;
    };
    auto compute = [&](int bi) {
        const char* Ar = lds[bi] + (wr * 64 + r) * 64 + off;
        const char* Br = lds[bi] + 8192 + (wc * 64 + r) * 64 + off;
        longlong2 av[4], bv[4];
        #pragma unroll
        for (int i = 0; i < 4; i++) {
            av[i] = *(const longlong2*)(Ar + i * 1024);
            bv[i] = *(const longlong2*)(Br + i * 1024);
        }
        #pragma unroll
        for (int i = 0; i < 4; i++)
            #pragma unroll
            for (int j = 0; j < 4; j++)
                acc[i][j] = __builtin_amdgcn_mfma_f32_16x16x32_fp8_fp8(av[i].x, bv[j].x, acc[i][j], 0, 0, 0);
        #pragma unroll
        for (int i = 0; i < 4; i++)
            #pragma unroll
            for (int j = 0; j < 4; j++)
                acc[i][j] = __builtin_amdgcn_mfma_f32_16x16x32_fp8_fp8(av[i].y, bv[j].y, acc[i][j], 0, 0, 0);
    };

    // depth-2 pipeline: computing step X with X+1, X+2 in flight (4 vm ops each)
    stage(0); stage(1);
    int cs = 2, cc = 0;
    #pragma unroll 1
    for (int it = 0; it < HD / BK - 2; ++it) {
        asm volatile("s_waitcnt vmcnt(4)" ::: "memory");   // step it landed
        __builtin_amdgcn_s_barrier();
        stage(cs); cs = (cs == 2) ? 0 : cs + 1;
        compute(cc); cc = (cc == 2) ? 0 : cc + 1;
    }
    asm volatile("s_waitcnt vmcnt(4)" ::: "memory");
    __builtin_amdgcn_s_barrier();
    compute(cc); cc = (cc == 2) ? 0 : cc + 1;
    asm volatile("s_waitcnt vmcnt(0)" ::: "memory");
    __builtin_amdgcn_s_barrier();
    compute(cc);

    // epilogue: descale (w1 was x8) + bias + gelu + w2 dot + 16-lane reduce
    float b1v[4], w20v[4], w21v[4];
    #pragma unroll
    for (int j = 0; j < 4; j++) {
        int cj = n0 + wc * 64 + j * 16 + r;
        b1v[j]  = b1[e * HD + cj];
        w20v[j] = w2[((size_t)e * HD + cj) * 2 + 0];
        w21v[j] = w2[((size_t)e * HD + cj) * 2 + 1];
    }
    #pragma unroll
    for (int i = 0; i < 4; i++) {
        #pragma unroll
        for (int reg = 0; reg < 4; reg++) {
            float s0 = 0.f, s1 = 0.f;
            #pragma unroll
            for (int j = 0; j < 4; j++) {
                float hv = gelu_exact(acc[i][j][reg] * 0.125f + b1v[j]);
                s0 += hv * w20v[j];
                s1 += hv * w21v[j];
            }
            #pragma unroll
            for (int offx = 1; offx < 16; offx <<= 1) {
                s0 += __shfl_xor(s0, offx);
                s1 += __shfl_xor(s1, offx);
            }
            if (r == 0) {
                int p = rt * BM + wr * 64 + i * 16 + 4 * h + reg;
                if (p < cnt) {
                    atomicAdd(&logits2c[(e * CAP + p) * 2 + 0], s0);
                    atomicAdd(&logits2c[(e * CAP + p) * 2 + 1], s1);
                }
            }
        }
    }
}

// ---- CE over (softmaxed) expert outputs (capacity-slot order) ---------------
__global__ __launch_bounds__(256) void ce_kernel(
    const float* __restrict__ logits2c, const float* __restrict__ b2,
    const int* __restrict__ cursor, const int* __restrict__ rowlist,
    const int* __restrict__ label, float* __restrict__ cesum)
{
    __shared__ float red[4];
    int tid = threadIdx.x;
    int s = blockIdx.x * 256 + tid;     // 0..NE*CAP-1
    int e = s / CAP;
    int local = s - e * CAP;
    int cnt = cursor[e]; if (cnt > CAP) cnt = CAP;
    float ce = 0.f;
    if (local < cnt) {
        int rr = rowlist[s];
        float l0 = logits2c[s * 2 + 0] + b2[e * 2 + 0];
        float l1 = logits2c[s * 2 + 1] + b2[e * 2 + 1];
        float mx = fmaxf(l0, l1);
        float e0 = expf(l0 - mx), e1 = expf(l1 - mx);
        float inv = 1.f / (e0 + e1);
        float p0 = e0 * inv, p1 = e1 * inv;
        float m2 = fmaxf(p0, p1);
        float z = m2 + logf(expf(p0 - m2) + expf(p1 - m2));
        float lp = ((label[rr] == 0) ? p0 : p1) - z;
        ce = -lp;
    }
    int lane = tid & 63, wave = tid >> 6;
    #pragma unroll
    for (int off = 32; off > 0; off >>= 1) ce += __shfl_xor(ce, off);
    if (lane == 0) red[wave] = ce;
    __syncthreads();
    if (tid == 0) atomicAdd(cesum, red[0] + red[1] + red[2] + red[3]);
}

// ---------------- finalize ----------------
__global__ void finalize_kernel(const float* __restrict__ S, const int* __restrict__ cursor,
                                const float* __restrict__ zsum, const float* __restrict__ cesum,
                                float* __restrict__ out)
{
    if (threadIdx.x == 0 && blockIdx.x == 0) {
        float bal = 0.f;
        for (int e = 0; e < NE; e++) bal += S[e] * (float)cursor[e];
        bal *= (float)NE / ((float)BQ * (float)BQ);
        out[0] = cesum[0] / (float)BQ + 0.01f * bal + 0.001f * (zsum[0] / (float)BQ);
    }
}

extern "C" void kernel_launch(void* const* d_in, const int* in_sizes, int n_in,
                              void* d_out, int out_size, void* d_ws, size_t ws_size,
                              hipStream_t stream) {
    const float* x      = (const float*)d_in[0];
    const int*   label  = (const int*)d_in[1];
    const float* gate_w = (const float*)d_in[2];
    const float* w1     = (const float*)d_in[3];
    const float* b1     = (const float*)d_in[4];
    const float* w2     = (const float*)d_in[5];
    const float* b2     = (const float*)d_in[6];
    float* out = (float*)d_out;

    char* ws = (char*)d_ws;
    int*   cursor   = (int*)(ws + WS_CURSOR);
    float* S        = (float*)(ws + WS_S);
    float* zsum     = (float*)(ws + WS_ZSUM);
    float* cesum    = (float*)(ws + WS_CESUM);
    int*   rowlist  = (int*)(ws + WS_ROWLIST);
    float* logits2c = (float*)(ws + WS_LOGITS2);
    unsigned char* xcq  = (unsigned char*)(ws + WS_XC);
    unsigned char* w1tq = (unsigned char*)(ws + WS_W1T);

    hipMemsetAsync(d_ws, 0, WS_HEAD, stream);

    prep_kernel<<<2304, 256, 0, stream>>>(x, gate_w, w1, cursor, S, zsum,
                                          rowlist, xcq, w1tq);
    expert_gemm_kernel<<<NE * TILES_PER_E, 256, 0, stream>>>(xcq, w1tq, b1, w2,
                                                             cursor, logits2c);
    ce_kernel<<<NE * CAP / 256, 256, 0, stream>>>(logits2c, b2, cursor, rowlist,
                                                  label, cesum);
    finalize_kernel<<<1, 64, 0, stream>>>(S, cursor, zsum, cesum, out);
}

// Round 15
// 72.378 us; speedup vs baseline: 1.1842x; 1.0126x over previous
//
#include <hip/hip_runtime.h>
#include <math.h>

#define BQ 8192
#define HD 1024
#define NE 8
#define CAP 1280

#define BM 128
#define BN 128
#define BK 64            // fp8 elements per K-step (64B rows, k-interleaved format)
#define NRT 10           // row tiles per expert (CAP/BM)
#define NCT 8            // col tiles (HD/BN)
#define TILES_PER_E 80

// k-interleaved segment format (64B = one BK slice of one row):
//   chunk c (16B) = bytes {k: 8c..8c+7} ++ {k: 32+8c..32+8c+7},  c = 0..3
// One ds_read_b128 at chunk h gives both K-half operands for MFMA lane (r,h).

// ---------------- workspace layout (bytes) ----------------
#define WS_CURSOR   0           // int[NE] (final == per-expert count)
#define WS_S        64          // float[NE]
#define WS_ZSUM     96          // float
#define WS_CESUM    100         // float
#define WS_ROWLIST  128         // int[NE*CAP] = 40960 -> ends 41088
#define WS_LOGITS2  41088       // float[NE*CAP*2] = 81920 -> ends 123008
#define WS_XC       123008      // fp8 xc [NE][CAP][HD] = 10485760 -> ends 10608768
#define WS_W1T      10608768    // fp8 w1^T*8 [NE][n][k] = 8388608

using f32x4  = __attribute__((ext_vector_type(4))) float;

__device__ __forceinline__ float gelu_exact(float v) {
    return 0.5f * v * (1.0f + erff(v * 0.70710678118654752440f));
}

// pack 4 floats -> 4 OCP e4m3 bytes (RNE, HW cvt)
__device__ __forceinline__ unsigned int f4_to_fp8x4(float f0, float f1, float f2, float f3) {
    int lo = __builtin_amdgcn_cvt_pk_fp8_f32(f0, f1, 0, false);
    return (unsigned int)__builtin_amdgcn_cvt_pk_fp8_f32(f2, f3, lo, true);
}

__device__ __forceinline__ void gll16(const void* g, void* l) {
    __builtin_amdgcn_global_load_lds((const __attribute__((address_space(1))) void*)g,
                                     (__attribute__((address_space(3))) void*)l, 16, 0, 0);
}

// ---- zero workspace head + logits2c (replaces pathological hipMemsetAsync) --
__global__ __launch_bounds__(256) void zero_kernel(float4* __restrict__ logits2c4,
                                                   int* __restrict__ head)
{
    int t = blockIdx.x * 256 + threadIdx.x;
    if (blockIdx.x == 0 && threadIdx.x < 32) head[threadIdx.x] = 0;   // 128B scalar head
    if (t < NE * CAP * 2 / 4)
        logits2c4[t] = make_float4(0.f, 0.f, 0.f, 0.f);
}

// ---- prep: router+compact (blocks 0..255) || w1 transpose (256..2303) -------
__global__ __launch_bounds__(256) void prep_kernel(
    const float* __restrict__ x, const float* __restrict__ gate_w,
    const float* __restrict__ w1,
    int* __restrict__ cursor, float* __restrict__ S, float* __restrict__ zsum,
    int* __restrict__ rowlist, unsigned char* __restrict__ xcq,
    unsigned char* __restrict__ w1tq)
{
    __shared__ __align__(16) char smem[33280];
    int tid = threadIdx.x;

    if (blockIdx.x >= 256) {
        // ---- transpose role: w1 fp32 [e][k][n] -> fp8(x8) [e][n][k-interleaved]
        char (*lt)[80] = (char (*)[80])smem;    // [n][k] bytes, 64x64 tile
        int tile = blockIdx.x - 256;          // 0..2047
        int e = tile >> 8;
        int rem = tile & 255;
        int k0 = (rem >> 4) << 6, n0 = (rem & 15) << 6;
        const float* src = w1 + ((size_t)e << 20) + (size_t)k0 * HD + n0;
        #pragma unroll
        for (int s = 0; s < 4; s++) {
            int q = tid + s * 256;
            int kk = q >> 4, n4 = q & 15;
            float4 v = *(const float4*)(src + (size_t)kk * HD + n4 * 4);
            unsigned int b = f4_to_fp8x4(v.x * 8.f, v.y * 8.f, v.z * 8.f, v.w * 8.f);
            lt[n4 * 4 + 0][kk] = (char)(b);
            lt[n4 * 4 + 1][kk] = (char)(b >> 8);
            lt[n4 * 4 + 2][kk] = (char)(b >> 16);
            lt[n4 * 4 + 3][kk] = (char)(b >> 24);
        }
        __syncthreads();
        // write 16B (groups 2q, 2q+1) as two 8B at k-interleaved positions
        int nn = tid >> 2, q = tid & 3;
        int pos0 = ((q & 1) << 5) | ((q >> 1) << 3);    // q:0->0, 1->32, 2->8, 3->40
        unsigned char* dst = w1tq + ((size_t)e << 20) + (size_t)(n0 + nn) * HD + k0;
        const unsigned long long* sp = (const unsigned long long*)&lt[nn][q * 16];
        *(unsigned long long*)(dst + pos0)      = sp[0];
        *(unsigned long long*)(dst + pos0 + 16) = sp[1];
        return;
    }

    // ---- router role: rows [bid*32, bid*32+32)
    float* gw    = (float*)smem;                    // 32 KB
    float* sS    = (float*)(smem + 32768);          // 8
    float* sZ    = (float*)(smem + 32800);          // 1
    int*   sBI   = (int*)(smem + 32832);            // 32
    int*   sSlot = (int*)(smem + 32960);            // 32
    int*   sBase = (int*)(smem + 33088);            // 8

    for (int i = tid * 4; i < NE * HD; i += 256 * 4) {
        *(float4*)(gw + i) = *(const float4*)(gate_w + i);
    }
    if (tid < NE) sS[tid] = 0.f;
    if (tid == 0) sZ[0] = 0.f;
    __syncthreads();

    int wave = tid >> 6, lane = tid & 63;
    int r0 = blockIdx.x * 32;
    float accS[NE];
    #pragma unroll
    for (int e = 0; e < NE; e++) accS[e] = 0.f;
    float accZ = 0.f;

    // phase 1: logits + per-row argmax
    #pragma unroll 1
    for (int i = 0; i < 8; i++) {
        int li = wave * 8 + i;
        int r = r0 + li;
        const float* xr = x + (size_t)r * HD;
        float acc[NE];
        #pragma unroll
        for (int e = 0; e < NE; e++) acc[e] = 0.f;
        #pragma unroll
        for (int it = 0; it < 4; it++) {
            int k = lane * 4 + it * 256;
            float4 xv = *(const float4*)(xr + k);
            #pragma unroll
            for (int e = 0; e < NE; e++) {
                const float* g = gw + e * HD + k;
                acc[e] += xv.x * g[0] + xv.y * g[1] + xv.z * g[2] + xv.w * g[3];
            }
        }
        #pragma unroll
        for (int e = 0; e < NE; e++) {
            #pragma unroll
            for (int off = 32; off > 0; off >>= 1)
                acc[e] += __shfl_xor(acc[e], off);
        }
        if (lane == 0) {
            float m = acc[0]; int bi = 0;
            #pragma unroll
            for (int e = 1; e < NE; e++) if (acc[e] > m) { m = acc[e]; bi = e; }
            float se = 0.f, ex[NE];
            #pragma unroll
            for (int e = 0; e < NE; e++) { ex[e] = expf(acc[e] - m); se += ex[e]; }
            float inv = 1.f / se;
            #pragma unroll
            for (int e = 0; e < NE; e++) accS[e] += ex[e] * inv;
            float lse = m + logf(se);
            accZ += lse * lse;
            sBI[li] = bi;
        }
    }
    if (lane == 0) {
        #pragma unroll
        for (int e = 0; e < NE; e++) atomicAdd(&sS[e], accS[e]);
        atomicAdd(sZ, accZ);
    }
    __syncthreads();

    // phase 2: block-level capacity reservation (8 atomics per block)
    if (tid < NE) {
        int cnt = 0;
        #pragma unroll
        for (int j = 0; j < 32; j++) cnt += (sBI[j] == tid);
        sBase[tid] = atomicAdd(&cursor[tid], cnt);
        atomicAdd(&S[tid], sS[tid]);
    }
    if (tid == 0) atomicAdd(zsum, sZ[0]);
    __syncthreads();

    // phase 3: per-row slot = base + rank
    if (tid < 32) {
        int bi = sBI[tid];
        int rank = 0;
        for (int j = 0; j < tid; j++) rank += (sBI[j] == bi);
        int slot = sBase[bi] + rank;
        sSlot[tid] = slot;
        if (slot < CAP) rowlist[bi * CAP + slot] = r0 + tid;
    }
    __syncthreads();

    // phase 4: re-read (hot) x rows, convert fp8, write k-interleaved slab
    #pragma unroll 1
    for (int i = 0; i < 8; i++) {
        int li = wave * 8 + i;
        int bi = sBI[li];
        int pos = sSlot[li];
        if (pos >= CAP) continue;
        const float* src = x + (size_t)(r0 + li) * HD + lane * 16;
        float4 v0 = *(const float4*)(src + 0);
        float4 v1 = *(const float4*)(src + 4);
        float4 v2 = *(const float4*)(src + 8);
        float4 v3 = *(const float4*)(src + 12);
        unsigned int g0a = f4_to_fp8x4(v0.x, v0.y, v0.z, v0.w);
        unsigned int g0b = f4_to_fp8x4(v1.x, v1.y, v1.z, v1.w);
        unsigned int g1a = f4_to_fp8x4(v2.x, v2.y, v2.z, v2.w);
        unsigned int g1b = f4_to_fp8x4(v3.x, v3.y, v3.z, v3.w);
        // lane covers segment s = lane>>2, groups 2q,2q+1 (q = lane&3)
        int s = lane >> 2, q = lane & 3;
        int pos0 = (s << 6) | ((q & 1) << 5) | ((q >> 1) << 3);
        unsigned char* dst = xcq + ((size_t)(bi * CAP + pos)) * HD;
        *(unsigned long long*)(dst + pos0)      = (unsigned long long)g0a | ((unsigned long long)g0b << 32);
        *(unsigned long long*)(dst + pos0 + 16) = (unsigned long long)g1a | ((unsigned long long)g1b << 32);
    }
}

// ---- MFMA expert GEMM (fp8): 128x128 tiles, 4 waves, 3 blocks/CU ------------
// grid 640: e = bid&7 (XCD round-robin); tix = bid>>3: col = tix/NRT, rt = tix%NRT
// (col-major tix -> same-XCD consecutive blocks share the B panel).
__global__ __launch_bounds__(256, 3) void expert_gemm_kernel(
    const unsigned char* __restrict__ xcq, const unsigned char* __restrict__ w1tq,
    const float* __restrict__ b1, const float* __restrict__ w2,
    const int* __restrict__ cursor, float* __restrict__ logits2c)
{
    int bid = blockIdx.x;
    int e = bid & 7;
    int tix = bid >> 3;
    int col = tix / NRT;
    int rt = tix - col * NRT;
    int cnt = cursor[e]; if (cnt > CAP) cnt = CAP;
    if (rt * BM >= cnt) return;
    int n0 = col * BN;

    // 3 buffers x [A 8KB | B 8KB] = 48KB
    __shared__ __align__(16) char lds[3][16384];

    int t = threadIdx.x;
    int l = t & 63;
    // staging pre-swizzle (rule 21): chunk' = (t&3) ^ ((row>>1)&3), row = t>>2
    int scolb = ((t & 3) ^ ((t >> 3) & 3)) << 4;
    int m = t >> 2;                               // 0..63

    int wid = t >> 6;                 // 0..3
    int wr = wid >> 1, wc = wid & 1;  // 2 x 2 wave grid, wave tile 64x64
    int r = l & 15, h = l >> 4;       // frag row/col = r, k-quad = h
    // single b128 read per fragment pair (proven 0-conflict pattern)
    int off = (h << 4) ^ (((r >> 1) & 3) << 4);

    const unsigned char* xcp  = xcq + ((size_t)e * CAP) * HD;
    const unsigned char* w1tp = w1tq + ((size_t)e << 20);

    const unsigned char* srcA0 = xcp + (size_t)(rt * BM + m) * HD + scolb;
    const unsigned char* srcA1 = srcA0 + (size_t)64 * HD;
    const unsigned char* srcB0 = w1tp + (size_t)(n0 + m) * HD + scolb;
    const unsigned char* srcB1 = srcB0 + (size_t)64 * HD;

    f32x4 acc[4][4];
    #pragma unroll
    for (int i = 0; i < 4; i++)
        #pragma unroll
        for (int j = 0; j < 4; j++) acc[i][j] = (f32x4)(0.f);

    auto stage = [&](int bi) {
        gll16(srcA0, lds[bi] + t * 16);         srcA0 += BK;
        gll16(srcA1, lds[bi] + 4096 + t * 16);  srcA1 += BK;
        gll16(srcB0, lds[bi] + 8192 + t * 16);  srcB0 += BK;
        gll16(srcB1, lds[bi] + 12288 + t * 16); srcB1 += BK;
    };
    auto compute = [&](int bi) {
        const char* Ar = lds[bi] + (wr * 64 + r) * 64 + off;
        const char* Br = lds[bi] + 8192 + (wc * 64 + r) * 64 + off;
        longlong2 av[4], bv[4];
        #pragma unroll
        for (int i = 0; i < 4; i++) {
            av[i] = *(const longlong2*)(Ar + i * 1024);
            bv[i] = *(const longlong2*)(Br + i * 1024);
        }
        #pragma unroll
        for (int i = 0; i < 4; i++)
            #pragma unroll
            for (int j = 0; j < 4; j++)
                acc[i][j] = __builtin_amdgcn_mfma_f32_16x16x32_fp8_fp8(av[i].x, bv[j].x, acc[i][j], 0, 0, 0);
        #pragma unroll
        for (int i = 0; i < 4; i++)
            #pragma unroll
            for (int j = 0; j < 4; j++)
                acc[i][j] = __builtin_amdgcn_mfma_f32_16x16x32_fp8_fp8(av[i].y, bv[j].y, acc[i][j], 0, 0, 0);
    };

    // depth-2 pipeline: computing step X with X+1, X+2 in flight (4 vm ops each)
    stage(0); stage(1);
    int cs = 2, cc = 0;
    #pragma unroll 1
    for (int it = 0; it < HD / BK - 2; ++it) {
        asm volatile("s_waitcnt vmcnt(4)" ::: "memory");   // step it landed
        __builtin_amdgcn_s_barrier();
        stage(cs); cs = (cs == 2) ? 0 : cs + 1;
        compute(cc); cc = (cc == 2) ? 0 : cc + 1;
    }
    asm volatile("s_waitcnt vmcnt(4)" ::: "memory");
    __builtin_amdgcn_s_barrier();
    compute(cc); cc = (cc == 2) ? 0 : cc + 1;
    asm volatile("s_waitcnt vmcnt(0)" ::: "memory");
    __builtin_amdgcn_s_barrier();
    compute(cc);

    // epilogue: descale (w1 was x8) + bias + gelu + w2 dot + 16-lane reduce
    float b1v[4], w20v[4], w21v[4];
    #pragma unroll
    for (int j = 0; j < 4; j++) {
        int cj = n0 + wc * 64 + j * 16 + r;
        b1v[j]  = b1[e * HD + cj];
        w20v[j] = w2[((size_t)e * HD + cj) * 2 + 0];
        w21v[j] = w2[((size_t)e * HD + cj) * 2 + 1];
    }
    #pragma unroll
    for (int i = 0; i < 4; i++) {
        #pragma unroll
        for (int reg = 0; reg < 4; reg++) {
            float s0 = 0.f, s1 = 0.f;
            #pragma unroll
            for (int j = 0; j < 4; j++) {
                float hv = gelu_exact(acc[i][j][reg] * 0.125f + b1v[j]);
                s0 += hv * w20v[j];
                s1 += hv * w21v[j];
            }
            #pragma unroll
            for (int offx = 1; offx < 16; offx <<= 1) {
                s0 += __shfl_xor(s0, offx);
                s1 += __shfl_xor(s1, offx);
            }
            if (r == 0) {
                int p = rt * BM + wr * 64 + i * 16 + 4 * h + reg;
                if (p < cnt) {
                    atomicAdd(&logits2c[(e * CAP + p) * 2 + 0], s0);
                    atomicAdd(&logits2c[(e * CAP + p) * 2 + 1], s1);
                }
            }
        }
    }
}

// ---- CE over (softmaxed) expert outputs (capacity-slot order) ---------------
__global__ __launch_bounds__(256) void ce_kernel(
    const float* __restrict__ logits2c, const float* __restrict__ b2,
    const int* __restrict__ cursor, const int* __restrict__ rowlist,
    const int* __restrict__ label, float* __restrict__ cesum)
{
    __shared__ float red[4];
    int tid = threadIdx.x;
    int s = blockIdx.x * 256 + tid;     // 0..NE*CAP-1
    int e = s / CAP;
    int local = s - e * CAP;
    int cnt = cursor[e]; if (cnt > CAP) cnt = CAP;
    float ce = 0.f;
    if (local < cnt) {
        int rr = rowlist[s];
        float l0 = logits2c[s * 2 + 0] + b2[e * 2 + 0];
        float l1 = logits2c[s * 2 + 1] + b2[e * 2 + 1];
        float mx = fmaxf(l0, l1);
        float e0 = expf(l0 - mx), e1 = expf(l1 - mx);
        float inv = 1.f / (e0 + e1);
        float p0 = e0 * inv, p1 = e1 * inv;
        float m2 = fmaxf(p0, p1);
        float z = m2 + logf(expf(p0 - m2) + expf(p1 - m2));
        float lp = ((label[rr] == 0) ? p0 : p1) - z;
        ce = -lp;
    }
    int lane = tid & 63, wave = tid >> 6;
    #pragma unroll
    for (int off = 32; off > 0; off >>= 1) ce += __shfl_xor(ce, off);
    if (lane == 0) red[wave] = ce;
    __syncthreads();
    if (tid == 0) atomicAdd(cesum, red[0] + red[1] + red[2] + red[3]);
}

// ---------------- finalize ----------------
__global__ void finalize_kernel(const float* __restrict__ S, const int* __restrict__ cursor,
                                const float* __restrict__ zsum, const float* __restrict__ cesum,
                                float* __restrict__ out)
{
    if (threadIdx.x == 0 && blockIdx.x == 0) {
        float bal = 0.f;
        for (int e = 0; e < NE; e++) bal += S[e] * (float)cursor[e];
        bal *= (float)NE / ((float)BQ * (float)BQ);
        out[0] = cesum[0] / (float)BQ + 0.01f * bal + 0.001f * (zsum[0] / (float)BQ);
    }
}

extern "C" void kernel_launch(void* const* d_in, const int* in_sizes, int n_in,
                              void* d_out, int out_size, void* d_ws, size_t ws_size,
                              hipStream_t stream) {
    const float* x      = (const float*)d_in[0];
    const int*   label  = (const int*)d_in[1];
    const float* gate_w = (const float*)d_in[2];
    const float* w1     = (const float*)d_in[3];
    const float* b1     = (const float*)d_in[4];
    const float* w2     = (const float*)d_in[5];
    const float* b2     = (const float*)d_in[6];
    float* out = (float*)d_out;

    char* ws = (char*)d_ws;
    int*   cursor   = (int*)(ws + WS_CURSOR);
    float* S        = (float*)(ws + WS_S);
    float* zsum     = (float*)(ws + WS_ZSUM);
    float* cesum    = (float*)(ws + WS_CESUM);
    int*   rowlist  = (int*)(ws + WS_ROWLIST);
    float* logits2c = (float*)(ws + WS_LOGITS2);
    unsigned char* xcq  = (unsigned char*)(ws + WS_XC);
    unsigned char* w1tq = (unsigned char*)(ws + WS_W1T);

    zero_kernel<<<(NE * CAP * 2 / 4 + 255) / 256, 256, 0, stream>>>(
        (float4*)logits2c, (int*)ws);
    prep_kernel<<<2304, 256, 0, stream>>>(x, gate_w, w1, cursor, S, zsum,
                                          rowlist, xcq, w1tq);
    expert_gemm_kernel<<<NE * TILES_PER_E, 256, 0, stream>>>(xcq, w1tq, b1, w2,
                                                             cursor, logits2c);
    ce_kernel<<<NE * CAP / 256, 256, 0, stream>>>(logits2c, b2, cursor, rowlist,
                                                  label, cesum);
    finalize_kernel<<<1, 64, 0, stream>>>(S, cursor, zsum, cesum, out);
}